// Round 6
// baseline (235.797 us; speedup 1.0000x reference)
//
#include <hip/hip_runtime.h>

// Problem constants
#define SEQ   2048
#define BATCH 2
#define DM    1024
#define NH    16
#define DKD   64
#define MROWS (SEQ*BATCH)   // 4096 rows of the [S,B,D] matrices

#define QSCALE 0.18033688011112042f   // (1/8)*log2(e), folded into Q projection

using bf16x8 = __attribute__((ext_vector_type(8))) __bf16;  // MFMA A/B frag (4 VGPRs)
using bf16x4 = __attribute__((ext_vector_type(4))) __bf16;  // 8B pack
using bf16x2 = __attribute__((ext_vector_type(2))) __bf16;  // 4B pack
using f32x4  = __attribute__((ext_vector_type(4))) float;   // MFMA C/D frag (16x16)
using f32x16 = __attribute__((ext_vector_type(16))) float;  // MFMA C/D frag (32x32)

// async global->LDS, 16B per lane; LDS dest must be wave-uniform base + lane*16
__device__ __forceinline__ void gld_lds16(const __bf16* g, __bf16* l) {
  __builtin_amdgcn_global_load_lds(
      (__attribute__((address_space(1))) void*)(g),
      (__attribute__((address_space(3))) void*)(l), 16, 0, 0);
}

// ------------------------------------------------------- fp32 -> bf16 (merged)
__global__ __launch_bounds__(256) void cvt_all(
    const float* __restrict__ s0, const float* __restrict__ s1,
    const float* __restrict__ s2, const float* __restrict__ s3,
    const float* __restrict__ s4, const float* __restrict__ s5,
    const float* __restrict__ s6,
    __bf16* __restrict__ d0, __bf16* __restrict__ d1, __bf16* __restrict__ d2,
    __bf16* __restrict__ d3, __bf16* __restrict__ d4, __bf16* __restrict__ d5,
    __bf16* __restrict__ d6, int n_big, int n_small) {
  int y = blockIdx.y;
  const float* s; __bf16* d;
  switch (y) {
    case 0: s = s0; d = d0; break;
    case 1: s = s1; d = d1; break;
    case 2: s = s2; d = d2; break;
    case 3: s = s3; d = d3; break;
    case 4: s = s4; d = d4; break;
    case 5: s = s5; d = d5; break;
    default: s = s6; d = d6; break;
  }
  int n = (y < 3) ? n_big : n_small;
  int i = (blockIdx.x * 256 + threadIdx.x) * 8;
  if (i >= n) return;
  const float4* sp = (const float4*)(s + i);
  float4 a = sp[0], b = sp[1];
  bf16x8 v;
  v[0]=(__bf16)a.x; v[1]=(__bf16)a.y; v[2]=(__bf16)a.z; v[3]=(__bf16)a.w;
  v[4]=(__bf16)b.x; v[5]=(__bf16)b.y; v[6]=(__bf16)b.z; v[7]=(__bf16)b.w;
  *(bf16x8*)(d + i) = v;
}

// ------------------------------------------- shared 128x128 GEMM-BT core, BK=64
// LDS tiles are [rows][64] with the XOR swizzle: the 16B granule at slot pp of
// row r holds global columns ((pp ^ (r&7))*8 .. +8). Staged via pre-swizzled
// GLOBAL source + linear LDS dest; frag reads XOR the granule with r&7.
__device__ __forceinline__ void gemm_core(const __bf16* __restrict__ A,
                                          const __bf16* __restrict__ Bt,
                                          __bf16* Ash, __bf16* Bsh,
                                          f32x4 acc[4][4], int m0, int n0) {
  const int K = DM;
  int tid = threadIdx.x;
  int lane = tid & 63, quad = lane >> 4, l16 = lane & 15, sw = l16 & 7;
  int w = tid >> 6;
  int wm = (w & 1) * 64, wn = (w >> 1) * 64;
  for (int k0 = 0; k0 < K; k0 += 64) {
    __syncthreads();
#pragma unroll
    for (int it = 0; it < 4; ++it) {
      int c   = tid + it * 256;          // 1024 chunks of 16B cover 128x64 bf16
      int row = c >> 3, pp = c & 7;
      int ko  = (pp ^ (row & 7)) << 3;   // pre-swizzled global column
      int base = (tid - lane + it * 256) * 8;  // wave-uniform LDS base (elems)
      gld_lds16(A  + (size_t)(m0 + row) * K + k0 + ko, Ash + base);
      gld_lds16(Bt + (size_t)(n0 + row) * K + k0 + ko, Bsh + base);
    }
    __syncthreads();  // drains vmcnt -> LDS valid
#pragma unroll
    for (int kk = 0; kk < 2; ++kk) {
      bf16x8 af[4], bfr[4];
#pragma unroll
      for (int mi = 0; mi < 4; mi++)
        af[mi] = *(const bf16x8*)&Ash[(wm + mi * 16 + l16) * 64 +
                                      (((kk * 4 + quad) ^ sw) << 3)];
#pragma unroll
      for (int ni = 0; ni < 4; ni++)
        bfr[ni] = *(const bf16x8*)&Bsh[(wn + ni * 16 + l16) * 64 +
                                       (((kk * 4 + quad) ^ sw) << 3)];
#pragma unroll
      for (int mi = 0; mi < 4; mi++)
#pragma unroll
        for (int ni = 0; ni < 4; ni++)
          acc[mi][ni] = __builtin_amdgcn_mfma_f32_16x16x32_bf16(
              af[mi], bfr[ni], acc[mi][ni], 0, 0, 0);
    }
  }
}

// ------------------------------------------ QKV projections, permuted bf16 out
// grid (8, 32, 3). Q/K out: [H][B][S][DK]; V out: [H][B][DK][S].
// Q output is pre-scaled by QSCALE (softmax fold) in fp32 -> exact.
__global__ __launch_bounds__(256, 3) void gemm_qkv(
    const __bf16* __restrict__ Xq, const __bf16* __restrict__ Xk,
    const __bf16* __restrict__ Xv, const __bf16* __restrict__ Wqkv,
    const float* __restrict__ bqp, const float* __restrict__ bkp,
    const float* __restrict__ bvp,
    __bf16* __restrict__ Qb, __bf16* __restrict__ Kb, __bf16* __restrict__ Vt) {
  __shared__ __bf16 Ash[128 * 64], Bsh[128 * 64];
  __shared__ __bf16 Esh[4][16 * 72];     // per-wave epilogue staging
  int z = blockIdx.z;
  const __bf16* A   = (z == 0) ? Xq : (z == 1) ? Xk : Xv;
  const __bf16* Bt  = Wqkv + (size_t)z * (DM * DM);
  const float* bias = (z == 0) ? bqp : (z == 1) ? bkp : bvp;
  int m0 = blockIdx.y * 128, n0 = blockIdx.x * 128;
  f32x4 acc[4][4] = {};
  gemm_core(A, Bt, Ash, Bsh, acc, m0, n0);

  int tid = threadIdx.x, lane = tid & 63, quad = lane >> 4, l16 = lane & 15;
  int w = tid >> 6, wm = (w & 1) * 64, wn = (w >> 1) * 64;
  __bf16* E = Esh[w];
  int n_base = n0 + wn;                  // 64-aligned -> one head per wave tile
  int hh = n_base >> 6;
  float scale = (z == 0) ? QSCALE : 1.0f;
  float bb[4];
#pragma unroll
  for (int ni = 0; ni < 4; ni++) bb[ni] = bias[n_base + ni * 16 + l16] * scale;

  if (z == 2) {
    // Vt[(hh*B+b)*64+dd][sg]: stage 16 dd-rows (one ni) at a time.
#pragma unroll
    for (int ni = 0; ni < 4; ni++) {
#pragma unroll
      for (int mi = 0; mi < 4; mi++) {
        int s0 = mi * 8 + quad * 2;      // local s (even)
        bf16x2 p0, p1;
        p0[0] = (__bf16)(acc[mi][ni][0] + bb[ni]);
        p0[1] = (__bf16)(acc[mi][ni][2] + bb[ni]);
        p1[0] = (__bf16)(acc[mi][ni][1] + bb[ni]);
        p1[1] = (__bf16)(acc[mi][ni][3] + bb[ni]);
        *(bf16x2*)&E[l16 * 72 + s0]      = p0;   // b = 0
        *(bf16x2*)&E[l16 * 72 + 32 + s0] = p1;   // b = 1
      }
      asm volatile("s_waitcnt lgkmcnt(0)" ::: "memory");
#pragma unroll
      for (int pass = 0; pass < 2; pass++) {
        int ddl = pass * 8 + (lane >> 3);
        int col = (lane & 7) * 8;
        bf16x8 v = *(const bf16x8*)&E[ddl * 72 + col];
        int b2 = col >> 5, sl = col & 31;
        int dd = ni * 16 + ddl;
        int sg = ((m0 + wm) >> 1) + sl;
        *(bf16x8*)&Vt[(((size_t)hh * BATCH + b2) * DKD + dd) * SEQ + sg] = v;
      }
      asm volatile("s_waitcnt lgkmcnt(0)" ::: "memory");
    }
  } else {
    __bf16* Out = (z == 0) ? Qb : Kb;
#pragma unroll
    for (int mi = 0; mi < 4; mi++) {
#pragma unroll
      for (int ni = 0; ni < 4; ni++)
#pragma unroll
        for (int r = 0; r < 4; r++)
          E[(quad * 4 + r) * 72 + ni * 16 + l16] =
              (__bf16)fmaf(acc[mi][ni][r], scale, bb[ni]);
      asm volatile("s_waitcnt lgkmcnt(0)" ::: "memory");
#pragma unroll
      for (int pass = 0; pass < 2; pass++) {
        int row16 = pass * 8 + (lane >> 3);
        int coll  = (lane & 7) * 8;
        bf16x8 v = *(const bf16x8*)&E[row16 * 72 + coll];
        int m = m0 + wm + mi * 16 + row16;
        int s = m >> 1, b2 = m & 1;
        *(bf16x8*)&Out[(((size_t)hh * BATCH + b2) * SEQ + s) * DKD + coll] = v;
      }
      asm volatile("s_waitcnt lgkmcnt(0)" ::: "memory");
    }
  }
}

// --------------------------------- output projection, 64x128 tiles, fp32 out
// Same BK=64 + swizzled staging as gemm_core.
__global__ __launch_bounds__(256, 3) void gemm_out(
    const __bf16* __restrict__ A, const __bf16* __restrict__ Bt,
    const float* __restrict__ bias, float* __restrict__ out) {
  __shared__ __bf16 Ash[64 * 64], Bsh[128 * 64];
  const int K = DM;
  int m0 = blockIdx.y * 64, n0 = blockIdx.x * 128;
  int tid = threadIdx.x;
  int lane = tid & 63, quad = lane >> 4, l16 = lane & 15, sw = l16 & 7;
  int w = tid >> 6;
  int wm = (w & 1) * 32, wn = (w >> 1) * 64;
  f32x4 acc[2][4] = {};
  for (int k0 = 0; k0 < K; k0 += 64) {
    __syncthreads();
#pragma unroll
    for (int it = 0; it < 2; ++it) {      // A: 512 chunks (64 rows x 8)
      int c = tid + it * 256;
      int row = c >> 3, pp = c & 7;
      int ko = (pp ^ (row & 7)) << 3;
      gld_lds16(A + (size_t)(m0 + row) * K + k0 + ko,
                Ash + (tid - lane + it * 256) * 8);
    }
#pragma unroll
    for (int it = 0; it < 4; ++it) {      // B: 1024 chunks (128 rows x 8)
      int c = tid + it * 256;
      int row = c >> 3, pp = c & 7;
      int ko = (pp ^ (row & 7)) << 3;
      gld_lds16(Bt + (size_t)(n0 + row) * K + k0 + ko,
                Bsh + (tid - lane + it * 256) * 8);
    }
    __syncthreads();
#pragma unroll
    for (int kk = 0; kk < 2; ++kk) {
      bf16x8 af[2], bfr[4];
#pragma unroll
      for (int mi = 0; mi < 2; mi++)
        af[mi] = *(const bf16x8*)&Ash[(wm + mi * 16 + l16) * 64 +
                                      (((kk * 4 + quad) ^ sw) << 3)];
#pragma unroll
      for (int ni = 0; ni < 4; ni++)
        bfr[ni] = *(const bf16x8*)&Bsh[(wn + ni * 16 + l16) * 64 +
                                       (((kk * 4 + quad) ^ sw) << 3)];
#pragma unroll
      for (int mi = 0; mi < 2; mi++)
#pragma unroll
        for (int ni = 0; ni < 4; ni++)
          acc[mi][ni] = __builtin_amdgcn_mfma_f32_16x16x32_bf16(
              af[mi], bfr[ni], acc[mi][ni], 0, 0, 0);
    }
  }
#pragma unroll
  for (int ni = 0; ni < 4; ni++) {
    int n = n0 + wn + ni * 16 + l16;
    float bb = bias[n];
#pragma unroll
    for (int mi = 0; mi < 2; mi++) {
#pragma unroll
      for (int r = 0; r < 4; r++) {
        int m = m0 + wm + mi * 16 + quad * 4 + r;
        out[(size_t)m * DM + n] = acc[mi][ni][r] + bb;
      }
    }
  }
}

// -------------------------------------------------------------- flash attention
// v6: v5's 32x32 in-register-softmax body + K/V-RANGE SPLIT across blocks.
// Occupancy analysis (round 5): total wave count at 32 q/wave is fixed at 2048
// = 8 waves/CU = 2/SIMD -> latency-bound (pipe demand ~25us, measured 63us).
// Fix: grid 1024; block n handles q-tile qi and j-HALF jh = n>>9 (16 of the 32
// K/V tiles), writing UNNORMALIZED fp32 O-partials + l-partials (softmax has
// no max-shift, so partials combine linearly in attn_combine). 4 blocks/CU ->
// 16 waves/CU with per-q LDS amortization intact.
// XCD: n%8 = hb%8 unchanged (hb = n&31); both j-halves of one (h,b) share XCD.
__global__ __launch_bounds__(256, 4) void flash_attn(
    const __bf16* __restrict__ Qg, const __bf16* __restrict__ Kg,
    const __bf16* __restrict__ Vtg,
    float* __restrict__ Op0, float* __restrict__ Op1,
    float* __restrict__ Lp0, float* __restrict__ Lp1) {
  __shared__ __bf16 Ksh[2][64 * 64];
  __shared__ __bf16 Vsh[2][64 * 64];
  int tid = threadIdx.x, w = tid >> 6, lane = tid & 63;
  int l32 = lane & 31, hf = lane >> 5;
  int n = blockIdx.x;
  int hb = n & 31, qi = (n >> 5) & 15, jh = n >> 9;
  int hd = hb >> 1, b = hb & 1, q0 = qi * 128;
  int qbase = q0 + w * 32;
  int t0 = jh * 16;                      // this block's K/V tile range
  float* Op = jh ? Op1 : Op0;
  float* Lp = jh ? Lp1 : Lp0;
  size_t hboff = ((size_t)hd * BATCH + b) * SEQ * DKD;
  const __bf16* Qp = Qg + hboff;
  const __bf16* Kp = Kg + hboff;
  const __bf16* Vp = Vtg + hboff;        // [DK][SEQ] within (h,b)

  // Q frags (MFMA B operand, 32x32x16): col q = l32, k-elems d = kd*16+hf*8+e
  bf16x8 qf[4];
#pragma unroll
  for (int kd = 0; kd < 4; kd++)
    qf[kd] = *(const bf16x8*)(
        Qp + (size_t)(qbase + l32) * DKD + kd * 16 + hf * 8);

  f32x16 o0 = {0,0,0,0,0,0,0,0,0,0,0,0,0,0,0,0};
  f32x16 o1 = {0,0,0,0,0,0,0,0,0,0,0,0,0,0,0,0};
  float l0 = 0.f, l1 = 0.f;              // split dep-chains

  // stage tile t0 into buf 0 (512 chunks K + 512 V over 256 threads)
#pragma unroll
  for (int it = 0; it < 2; ++it) {
    int c = tid + it * 256;
    int r = c >> 3, pp = c & 7;
    int off = (pp ^ (r & 7)) << 3;
    gld_lds16(Kp + (size_t)(t0 * 64 + r) * DKD + off, Ksh[0] + c * 8);
    gld_lds16(Vp + (size_t)r * SEQ + t0 * 64 + off, Vsh[0] + c * 8);
  }

  for (int tt = 0; tt < 16; ++tt) {
    __syncthreads();                       // drains DMA for buf[tt&1]
    if (tt + 1 < 16) {
      int k0n = (t0 + tt + 1) * 64, bn = (tt + 1) & 1;
#pragma unroll
      for (int it = 0; it < 2; ++it) {
        int c = tid + it * 256;
        int r = c >> 3, pp = c & 7;
        int off = (pp ^ (r & 7)) << 3;
        gld_lds16(Kp + (size_t)(k0n + r) * DKD + off, Ksh[bn] + c * 8);
        gld_lds16(Vp + (size_t)r * SEQ + k0n + off, Vsh[bn] + c * 8);
      }
    }
    const __bf16* Kb_ = Ksh[tt & 1];
    const __bf16* Vb_ = Vsh[tt & 1];

#pragma unroll
    for (int jt = 0; jt < 2; ++jt) {
      // S^T = K . Q^T over this 32-j block
      int rk = jt * 32 + l32;
      f32x16 s = {0,0,0,0,0,0,0,0,0,0,0,0,0,0,0,0};
#pragma unroll
      for (int kd = 0; kd < 4; kd++) {
        bf16x8 kf = *(const bf16x8*)&Kb_[rk * 64 +
                                         (((kd * 2 + hf) ^ (rk & 7)) << 3)];
        s = __builtin_amdgcn_mfma_f32_32x32x16_bf16(kf, qf[kd], s, 0, 0, 0);
      }
      // exp2 + cvt_pk pack: L[bq][sl] holds bf16 pair (j = bq*8+4*hf + 2*sl,+1)
      unsigned L[4][2];
#pragma unroll
      for (int bq = 0; bq < 4; bq++) {
        float p0 = exp2f(s[4 * bq + 0]);
        float p1 = exp2f(s[4 * bq + 1]);
        float p2 = exp2f(s[4 * bq + 2]);
        float p3 = exp2f(s[4 * bq + 3]);
        l0 += p0 + p2;
        l1 += p1 + p3;
        asm("v_cvt_pk_bf16_f32 %0, %1, %2" : "=v"(L[bq][0]) : "v"(p0), "v"(p1));
        asm("v_cvt_pk_bf16_f32 %0, %1, %2" : "=v"(L[bq][1]) : "v"(p2), "v"(p3));
      }
      // cross-half exchange + PV, per 16-j mfma slice
#pragma unroll
      for (int kp = 0; kp < 2; kp++) {
        unsigned a0 = L[2 * kp][0], b0 = L[2 * kp + 1][0];
        unsigned a1 = L[2 * kp][1], b1 = L[2 * kp + 1][1];
        // after swap: a' = [a_lo | b_lo] (pa words 0..1), b' = [a_hi | b_hi]
        asm("v_permlane32_swap_b32 %0, %1" : "+v"(a0), "+v"(b0));
        asm("v_permlane32_swap_b32 %0, %1" : "+v"(a1), "+v"(b1));
        unsigned pw[4] = {a0, a1, b0, b1};
        bf16x8 pa;
        __builtin_memcpy(&pa, pw, 16);
        int ks = jt * 2 + kp;
        {
          int rv = l32;                  // d-half 0
          bf16x8 vb = *(const bf16x8*)&Vb_[rv * 64 +
                                           (((ks * 2 + hf) ^ (rv & 7)) << 3)];
          o0 = __builtin_amdgcn_mfma_f32_32x32x16_bf16(pa, vb, o0, 0, 0, 0);
        }
        {
          int rv = 32 + l32;             // d-half 1
          bf16x8 vb = *(const bf16x8*)&Vb_[rv * 64 +
                                           (((ks * 2 + hf) ^ (rv & 7)) << 3)];
          o1 = __builtin_amdgcn_mfma_f32_32x32x16_bf16(pa, vb, o1, 0, 0, 0);
        }
      }
    }
  }

  // l: lane halves hold disjoint j-subsets for the same q = qbase + l32
  float l_ = l0 + l1;
  l_ += __shfl_xor(l_, 32, 64);
  if (hf == 0)
    Lp[((size_t)hd * BATCH + b) * SEQ + qbase + l32] = l_;

  // store UNNORMALIZED fp32 partials; o regs hold q = (r&3)+8*(r>>2)+4*hf
#pragma unroll
  for (int r = 0; r < 16; ++r) {
    int qrow = (r & 3) + 8 * (r >> 2) + 4 * hf;
    int q = qbase + qrow;
    float* dst = Op + ((size_t)q * BATCH + b) * DM + hd * DKD;
    dst[l32]      = o0[r];
    dst[32 + l32] = o1[r];
  }
}

// ------------------------------- combine j-half partials: Xa = (O0+O1)/(l0+l1)
__global__ __launch_bounds__(256) void attn_combine(
    const float* __restrict__ Op0, const float* __restrict__ Op1,
    const float* __restrict__ Lp0, const float* __restrict__ Lp1,
    __bf16* __restrict__ Xa) {
  int i = (blockIdx.x * 256 + threadIdx.x) * 8;   // 8 elems, one head each
  int row = i >> 10, col = i & 1023;              // row = q*BATCH+b
  int q = row >> 1, b = row & 1, h = col >> 6;
  size_t li = ((size_t)h * BATCH + b) * SEQ + q;
  float linv = 1.0f / (Lp0[li] + Lp1[li]);
  const float4* a = (const float4*)(Op0 + i);
  const float4* c = (const float4*)(Op1 + i);
  float4 a0 = a[0], a1 = a[1], c0 = c[0], c1 = c[1];
  bf16x8 v;
  v[0] = (__bf16)((a0.x + c0.x) * linv);
  v[1] = (__bf16)((a0.y + c0.y) * linv);
  v[2] = (__bf16)((a0.z + c0.z) * linv);
  v[3] = (__bf16)((a0.w + c0.w) * linv);
  v[4] = (__bf16)((a1.x + c1.x) * linv);
  v[5] = (__bf16)((a1.y + c1.y) * linv);
  v[6] = (__bf16)((a1.z + c1.z) * linv);
  v[7] = (__bf16)((a1.w + c1.w) * linv);
  *(bf16x8*)(Xa + i) = v;
}

// ------------------------------------------------------------------- launcher
extern "C" void kernel_launch(void* const* d_in, const int* in_sizes, int n_in,
                              void* d_out, int out_size, void* d_ws,
                              size_t ws_size, hipStream_t stream) {
  (void)in_sizes; (void)n_in; (void)out_size; (void)ws_size;
  const float* query = (const float*)d_in[0];
  const float* key_  = (const float*)d_in[1];
  const float* value = (const float*)d_in[2];
  const float* Wq = (const float*)d_in[3];
  const float* bq = (const float*)d_in[4];
  const float* Wk = (const float*)d_in[5];
  const float* bk = (const float*)d_in[6];
  const float* Wv = (const float*)d_in[7];
  const float* bv = (const float*)d_in[8];
  const float* Wo = (const float*)d_in[9];
  const float* bo = (const float*)d_in[10];

  const size_t NX = (size_t)MROWS * DM;  // 4M elems
  const size_t NW = (size_t)DM * DM;     // 1M elems
  const size_t NL = (size_t)NH * BATCH * SEQ;  // 64K l-partials
  __bf16* p    = (__bf16*)d_ws;
  __bf16* Xq   = p; p += NX;             // reused as Xa after gemm_qkv
  __bf16* Xk   = p; p += NX;             // reused as Op0 (fp32) after gemm_qkv
  __bf16* Xv   = p; p += NX;             //   (Xk+Xv = 16MB = NX fp32)
  __bf16* Wqkv = p; p += 3 * NW;
  __bf16* Wob  = p; p += NW;
  __bf16* Qb   = p; p += NX;   // [H][B][S][DK], pre-scaled by QSCALE
  __bf16* Kb   = p; p += NX;   // [H][B][S][DK]
  __bf16* Vt   = p; p += NX;   // [H][B][DK][S]
  float*  Op1  = (float*)p; p += 2 * NX; // fp32 j-half-1 O partial (16MB)
  float*  Lp0  = (float*)p; p += 2 * NL;
  float*  Lp1  = (float*)p; p += 2 * NL;
  float*  Op0  = (float*)Xk;   // aliases Xk+Xv (dead after gemm_qkv)
  __bf16* Xa   = Xq;           // [S*B][D] (aliases Xq, dead after gemm_qkv)

  cvt_all<<<dim3((unsigned)(NX / 2048), 7), 256, 0, stream>>>(
      query, key_, value, Wq, Wk, Wv, Wo,
      Xq, Xk, Xv, Wqkv, Wqkv + NW, Wqkv + 2 * NW, Wob, (int)NX, (int)NW);

  gemm_qkv<<<dim3(DM / 128, MROWS / 128, 3), 256, 0, stream>>>(
      Xq, Xk, Xv, Wqkv, bq, bk, bv, Qb, Kb, Vt);
  flash_attn<<<dim3(1024), 256, 0, stream>>>(Qb, Kb, Vt, Op0, Op1, Lp0, Lp1);
  attn_combine<<<dim3((unsigned)(NX / 2048)), 256, 0, stream>>>(
      Op0, Op1, Lp0, Lp1, Xa);
  gemm_out<<<dim3(DM / 128, MROWS / 64), 256, 0, stream>>>(
      Xa, Wob, bo, (float*)d_out);
}

// Round 7
// 226.208 us; speedup vs baseline: 1.0424x; 1.0424x over previous
//
#include <hip/hip_runtime.h>

// Problem constants
#define SEQ   2048
#define BATCH 2
#define DM    1024
#define NH    16
#define DKD   64
#define MROWS (SEQ*BATCH)   // 4096 rows of the [S,B,D] matrices

#define QSCALE 0.18033688011112042f   // (1/8)*log2(e), folded into Q projection

using bf16x8 = __attribute__((ext_vector_type(8))) __bf16;  // MFMA A/B frag (4 VGPRs)
using bf16x4 = __attribute__((ext_vector_type(4))) __bf16;  // 8B pack
using bf16x2 = __attribute__((ext_vector_type(2))) __bf16;  // 4B pack
using f32x4  = __attribute__((ext_vector_type(4))) float;   // MFMA C/D frag (16x16)
using f32x16 = __attribute__((ext_vector_type(16))) float;  // MFMA C/D frag (32x32)

// async global->LDS, 16B per lane; LDS dest must be wave-uniform base + lane*16
__device__ __forceinline__ void gld_lds16(const __bf16* g, __bf16* l) {
  __builtin_amdgcn_global_load_lds(
      (__attribute__((address_space(1))) void*)(g),
      (__attribute__((address_space(3))) void*)(l), 16, 0, 0);
}

// ------------------------------------------------------- fp32 -> bf16 (merged)
__global__ __launch_bounds__(256) void cvt_all(
    const float* __restrict__ s0, const float* __restrict__ s1,
    const float* __restrict__ s2, const float* __restrict__ s3,
    const float* __restrict__ s4, const float* __restrict__ s5,
    const float* __restrict__ s6,
    __bf16* __restrict__ d0, __bf16* __restrict__ d1, __bf16* __restrict__ d2,
    __bf16* __restrict__ d3, __bf16* __restrict__ d4, __bf16* __restrict__ d5,
    __bf16* __restrict__ d6, int n_big, int n_small) {
  int y = blockIdx.y;
  const float* s; __bf16* d;
  switch (y) {
    case 0: s = s0; d = d0; break;
    case 1: s = s1; d = d1; break;
    case 2: s = s2; d = d2; break;
    case 3: s = s3; d = d3; break;
    case 4: s = s4; d = d4; break;
    case 5: s = s5; d = d5; break;
    default: s = s6; d = d6; break;
  }
  int n = (y < 3) ? n_big : n_small;
  int i = (blockIdx.x * 256 + threadIdx.x) * 8;
  if (i >= n) return;
  const float4* sp = (const float4*)(s + i);
  float4 a = sp[0], b = sp[1];
  bf16x8 v;
  v[0]=(__bf16)a.x; v[1]=(__bf16)a.y; v[2]=(__bf16)a.z; v[3]=(__bf16)a.w;
  v[4]=(__bf16)b.x; v[5]=(__bf16)b.y; v[6]=(__bf16)b.z; v[7]=(__bf16)b.w;
  *(bf16x8*)(d + i) = v;
}

// ------------------------------------------- shared 128x128 GEMM-BT core, BK=64
// LDS tiles are [rows][64] with the XOR swizzle: the 16B granule at slot pp of
// row r holds global columns ((pp ^ (r&7))*8 .. +8). Staged via pre-swizzled
// GLOBAL source + linear LDS dest; frag reads XOR the granule with r&7.
__device__ __forceinline__ void gemm_core(const __bf16* __restrict__ A,
                                          const __bf16* __restrict__ Bt,
                                          __bf16* Ash, __bf16* Bsh,
                                          f32x4 acc[4][4], int m0, int n0) {
  const int K = DM;
  int tid = threadIdx.x;
  int lane = tid & 63, quad = lane >> 4, l16 = lane & 15, sw = l16 & 7;
  int w = tid >> 6;
  int wm = (w & 1) * 64, wn = (w >> 1) * 64;
  for (int k0 = 0; k0 < K; k0 += 64) {
    __syncthreads();
#pragma unroll
    for (int it = 0; it < 4; ++it) {
      int c   = tid + it * 256;          // 1024 chunks of 16B cover 128x64 bf16
      int row = c >> 3, pp = c & 7;
      int ko  = (pp ^ (row & 7)) << 3;   // pre-swizzled global column
      int base = (tid - lane + it * 256) * 8;  // wave-uniform LDS base (elems)
      gld_lds16(A  + (size_t)(m0 + row) * K + k0 + ko, Ash + base);
      gld_lds16(Bt + (size_t)(n0 + row) * K + k0 + ko, Bsh + base);
    }
    __syncthreads();  // drains vmcnt -> LDS valid
#pragma unroll
    for (int kk = 0; kk < 2; ++kk) {
      bf16x8 af[4], bfr[4];
#pragma unroll
      for (int mi = 0; mi < 4; mi++)
        af[mi] = *(const bf16x8*)&Ash[(wm + mi * 16 + l16) * 64 +
                                      (((kk * 4 + quad) ^ sw) << 3)];
#pragma unroll
      for (int ni = 0; ni < 4; ni++)
        bfr[ni] = *(const bf16x8*)&Bsh[(wn + ni * 16 + l16) * 64 +
                                       (((kk * 4 + quad) ^ sw) << 3)];
#pragma unroll
      for (int mi = 0; mi < 4; mi++)
#pragma unroll
        for (int ni = 0; ni < 4; ni++)
          acc[mi][ni] = __builtin_amdgcn_mfma_f32_16x16x32_bf16(
              af[mi], bfr[ni], acc[mi][ni], 0, 0, 0);
    }
  }
}

// ------------------------------------------ QKV projections, permuted bf16 out
// grid (8, 32, 3). Q/K out: [H][B][S][DK]; V out: [H][B][DK][S].
// Q output is pre-scaled by QSCALE (softmax fold) in fp32 -> exact.
__global__ __launch_bounds__(256, 3) void gemm_qkv(
    const __bf16* __restrict__ Xq, const __bf16* __restrict__ Xk,
    const __bf16* __restrict__ Xv, const __bf16* __restrict__ Wqkv,
    const float* __restrict__ bqp, const float* __restrict__ bkp,
    const float* __restrict__ bvp,
    __bf16* __restrict__ Qb, __bf16* __restrict__ Kb, __bf16* __restrict__ Vt) {
  __shared__ __bf16 Ash[128 * 64], Bsh[128 * 64];
  __shared__ __bf16 Esh[4][16 * 72];     // per-wave epilogue staging
  int z = blockIdx.z;
  const __bf16* A   = (z == 0) ? Xq : (z == 1) ? Xk : Xv;
  const __bf16* Bt  = Wqkv + (size_t)z * (DM * DM);
  const float* bias = (z == 0) ? bqp : (z == 1) ? bkp : bvp;
  int m0 = blockIdx.y * 128, n0 = blockIdx.x * 128;
  f32x4 acc[4][4] = {};
  gemm_core(A, Bt, Ash, Bsh, acc, m0, n0);

  int tid = threadIdx.x, lane = tid & 63, quad = lane >> 4, l16 = lane & 15;
  int w = tid >> 6, wm = (w & 1) * 64, wn = (w >> 1) * 64;
  __bf16* E = Esh[w];
  int n_base = n0 + wn;                  // 64-aligned -> one head per wave tile
  int hh = n_base >> 6;
  float scale = (z == 0) ? QSCALE : 1.0f;
  float bb[4];
#pragma unroll
  for (int ni = 0; ni < 4; ni++) bb[ni] = bias[n_base + ni * 16 + l16] * scale;

  if (z == 2) {
    // Vt[(hh*B+b)*64+dd][sg]: stage 16 dd-rows (one ni) at a time.
#pragma unroll
    for (int ni = 0; ni < 4; ni++) {
#pragma unroll
      for (int mi = 0; mi < 4; mi++) {
        int s0 = mi * 8 + quad * 2;      // local s (even)
        bf16x2 p0, p1;
        p0[0] = (__bf16)(acc[mi][ni][0] + bb[ni]);
        p0[1] = (__bf16)(acc[mi][ni][2] + bb[ni]);
        p1[0] = (__bf16)(acc[mi][ni][1] + bb[ni]);
        p1[1] = (__bf16)(acc[mi][ni][3] + bb[ni]);
        *(bf16x2*)&E[l16 * 72 + s0]      = p0;   // b = 0
        *(bf16x2*)&E[l16 * 72 + 32 + s0] = p1;   // b = 1
      }
      asm volatile("s_waitcnt lgkmcnt(0)" ::: "memory");
#pragma unroll
      for (int pass = 0; pass < 2; pass++) {
        int ddl = pass * 8 + (lane >> 3);
        int col = (lane & 7) * 8;
        bf16x8 v = *(const bf16x8*)&E[ddl * 72 + col];
        int b2 = col >> 5, sl = col & 31;
        int dd = ni * 16 + ddl;
        int sg = ((m0 + wm) >> 1) + sl;
        *(bf16x8*)&Vt[(((size_t)hh * BATCH + b2) * DKD + dd) * SEQ + sg] = v;
      }
      asm volatile("s_waitcnt lgkmcnt(0)" ::: "memory");
    }
  } else {
    __bf16* Out = (z == 0) ? Qb : Kb;
#pragma unroll
    for (int mi = 0; mi < 4; mi++) {
#pragma unroll
      for (int ni = 0; ni < 4; ni++)
#pragma unroll
        for (int r = 0; r < 4; r++)
          E[(quad * 4 + r) * 72 + ni * 16 + l16] =
              (__bf16)fmaf(acc[mi][ni][r], scale, bb[ni]);
      asm volatile("s_waitcnt lgkmcnt(0)" ::: "memory");
#pragma unroll
      for (int pass = 0; pass < 2; pass++) {
        int row16 = pass * 8 + (lane >> 3);
        int coll  = (lane & 7) * 8;
        bf16x8 v = *(const bf16x8*)&E[row16 * 72 + coll];
        int m = m0 + wm + mi * 16 + row16;
        int s = m >> 1, b2 = m & 1;
        *(bf16x8*)&Out[(((size_t)hh * BATCH + b2) * SEQ + s) * DKD + coll] = v;
      }
      asm volatile("s_waitcnt lgkmcnt(0)" ::: "memory");
    }
  }
}

// --------------------------------- output projection, 64x128 tiles, fp32 out
// Same BK=64 + swizzled staging as gemm_core.
__global__ __launch_bounds__(256, 3) void gemm_out(
    const __bf16* __restrict__ A, const __bf16* __restrict__ Bt,
    const float* __restrict__ bias, float* __restrict__ out) {
  __shared__ __bf16 Ash[64 * 64], Bsh[128 * 64];
  const int K = DM;
  int m0 = blockIdx.y * 64, n0 = blockIdx.x * 128;
  int tid = threadIdx.x;
  int lane = tid & 63, quad = lane >> 4, l16 = lane & 15, sw = l16 & 7;
  int w = tid >> 6;
  int wm = (w & 1) * 32, wn = (w >> 1) * 64;
  f32x4 acc[2][4] = {};
  for (int k0 = 0; k0 < K; k0 += 64) {
    __syncthreads();
#pragma unroll
    for (int it = 0; it < 2; ++it) {      // A: 512 chunks (64 rows x 8)
      int c = tid + it * 256;
      int row = c >> 3, pp = c & 7;
      int ko = (pp ^ (row & 7)) << 3;
      gld_lds16(A + (size_t)(m0 + row) * K + k0 + ko,
                Ash + (tid - lane + it * 256) * 8);
    }
#pragma unroll
    for (int it = 0; it < 4; ++it) {      // B: 1024 chunks (128 rows x 8)
      int c = tid + it * 256;
      int row = c >> 3, pp = c & 7;
      int ko = (pp ^ (row & 7)) << 3;
      gld_lds16(Bt + (size_t)(n0 + row) * K + k0 + ko,
                Bsh + (tid - lane + it * 256) * 8);
    }
    __syncthreads();
#pragma unroll
    for (int kk = 0; kk < 2; ++kk) {
      bf16x8 af[2], bfr[4];
#pragma unroll
      for (int mi = 0; mi < 2; mi++)
        af[mi] = *(const bf16x8*)&Ash[(wm + mi * 16 + l16) * 64 +
                                      (((kk * 4 + quad) ^ sw) << 3)];
#pragma unroll
      for (int ni = 0; ni < 4; ni++)
        bfr[ni] = *(const bf16x8*)&Bsh[(wn + ni * 16 + l16) * 64 +
                                       (((kk * 4 + quad) ^ sw) << 3)];
#pragma unroll
      for (int mi = 0; mi < 2; mi++)
#pragma unroll
        for (int ni = 0; ni < 4; ni++)
          acc[mi][ni] = __builtin_amdgcn_mfma_f32_16x16x32_bf16(
              af[mi], bfr[ni], acc[mi][ni], 0, 0, 0);
    }
  }
#pragma unroll
  for (int ni = 0; ni < 4; ni++) {
    int n = n0 + wn + ni * 16 + l16;
    float bb = bias[n];
#pragma unroll
    for (int mi = 0; mi < 2; mi++) {
#pragma unroll
      for (int r = 0; r < 4; r++) {
        int m = m0 + wm + mi * 16 + quad * 4 + r;
        out[(size_t)m * DM + n] = acc[mi][ni][r] + bb;
      }
    }
  }
}

// -------------------------------------------------------------- flash attention
// v7 = v5 (round-5 known-good 32x32 in-register-softmax, 62.8us) + MFMA-l:
// the softmax denominator is accumulated on the MATRIX pipe instead of VALU.
// Round-6 A/B showed occupancy 18->33% gives zero pipe-fill gain (VALUBusy/
// MfmaUtil flat) -> v5 is VALU/chain-limited, not TLP-starved. VALU carries
// ~290cyc/tile/wave (54% busy); MFMA only 21%. Moving the 32 l-adds/tile to
// 4 extra mfma(pa, ones) per tile (B = all-ones -> every output row r gets
// sum_j P[q(r)][j], replicated across lanes) removes both serial fp32 chains
// AND the final shuffles; l now sums the same bf16-rounded p that PV consumes.
// Grid 512 x 4 waves; wave owns 32 q; K/V swizzle-staged dbuf; 1 barrier/tile.
// Block n: hb = n&31 (h=hb>>1, b=hb&1), qi = n>>5 -> XCD = hb%8 L2 locality.
__global__ __launch_bounds__(256, 2) void flash_attn(
    const __bf16* __restrict__ Qg, const __bf16* __restrict__ Kg,
    const __bf16* __restrict__ Vtg, __bf16* __restrict__ Xa) {
  __shared__ __bf16 Ksh[2][64 * 64];
  __shared__ __bf16 Vsh[2][64 * 64];
  int tid = threadIdx.x, w = tid >> 6, lane = tid & 63;
  int l32 = lane & 31, hf = lane >> 5;
  int n = blockIdx.x;
  int hb = n & 31, qi = n >> 5;
  int hd = hb >> 1, b = hb & 1, q0 = qi * 128;
  int qbase = q0 + w * 32;
  size_t hboff = ((size_t)hd * BATCH + b) * SEQ * DKD;
  const __bf16* Qp = Qg + hboff;
  const __bf16* Kp = Kg + hboff;
  const __bf16* Vp = Vtg + hboff;        // [DK][SEQ] within (h,b)

  // Q frags (MFMA B operand, 32x32x16): col q = l32, k-elems d = kd*16+hf*8+e
  bf16x8 qf[4];
#pragma unroll
  for (int kd = 0; kd < 4; kd++)
    qf[kd] = *(const bf16x8*)(
        Qp + (size_t)(qbase + l32) * DKD + kd * 16 + hf * 8);

  // all-ones B frag for the l-row-sum MFMA
  bf16x8 onesf;
#pragma unroll
  for (int e = 0; e < 8; e++) onesf[e] = (__bf16)1.0f;

  f32x16 o0 = {0,0,0,0,0,0,0,0,0,0,0,0,0,0,0,0};
  f32x16 o1 = {0,0,0,0,0,0,0,0,0,0,0,0,0,0,0,0};
  f32x16 lacc = {0,0,0,0,0,0,0,0,0,0,0,0,0,0,0,0};

  // stage tile 0 into buf 0 (512 chunks K + 512 V over 256 threads)
#pragma unroll
  for (int it = 0; it < 2; ++it) {
    int c = tid + it * 256;
    int r = c >> 3, pp = c & 7;
    int off = (pp ^ (r & 7)) << 3;
    gld_lds16(Kp + (size_t)r * DKD + off, Ksh[0] + c * 8);
    gld_lds16(Vp + (size_t)r * SEQ + off, Vsh[0] + c * 8);
  }

  for (int t = 0; t < SEQ / 64; ++t) {
    __syncthreads();                       // drains DMA for buf[t&1]
    if (t + 1 < SEQ / 64) {
      int k0n = (t + 1) * 64, bn = (t + 1) & 1;
#pragma unroll
      for (int it = 0; it < 2; ++it) {
        int c = tid + it * 256;
        int r = c >> 3, pp = c & 7;
        int off = (pp ^ (r & 7)) << 3;
        gld_lds16(Kp + (size_t)(k0n + r) * DKD + off, Ksh[bn] + c * 8);
        gld_lds16(Vp + (size_t)r * SEQ + k0n + off, Vsh[bn] + c * 8);
      }
    }
    const __bf16* Kb_ = Ksh[t & 1];
    const __bf16* Vb_ = Vsh[t & 1];

#pragma unroll
    for (int jt = 0; jt < 2; ++jt) {
      // S^T = K . Q^T over this 32-j block
      int rk = jt * 32 + l32;
      f32x16 s = {0,0,0,0,0,0,0,0,0,0,0,0,0,0,0,0};
#pragma unroll
      for (int kd = 0; kd < 4; kd++) {
        bf16x8 kf = *(const bf16x8*)&Kb_[rk * 64 +
                                         (((kd * 2 + hf) ^ (rk & 7)) << 3)];
        s = __builtin_amdgcn_mfma_f32_32x32x16_bf16(kf, qf[kd], s, 0, 0, 0);
      }
      // exp2 + cvt_pk pack: L[bq][sl] holds bf16 pair (j = bq*8+4*hf + 2*sl,+1)
      unsigned L[4][2];
#pragma unroll
      for (int bq = 0; bq < 4; bq++) {
        float p0 = exp2f(s[4 * bq + 0]);
        float p1 = exp2f(s[4 * bq + 1]);
        float p2 = exp2f(s[4 * bq + 2]);
        float p3 = exp2f(s[4 * bq + 3]);
        asm("v_cvt_pk_bf16_f32 %0, %1, %2" : "=v"(L[bq][0]) : "v"(p0), "v"(p1));
        asm("v_cvt_pk_bf16_f32 %0, %1, %2" : "=v"(L[bq][1]) : "v"(p2), "v"(p3));
      }
      // cross-half exchange + PV (+ l row-sum on MFMA pipe), per 16-j slice
#pragma unroll
      for (int kp = 0; kp < 2; kp++) {
        unsigned a0 = L[2 * kp][0], b0 = L[2 * kp + 1][0];
        unsigned a1 = L[2 * kp][1], b1 = L[2 * kp + 1][1];
        // after swap: a' = [a_lo | b_lo] (pa words 0..1), b' = [a_hi | b_hi]
        asm("v_permlane32_swap_b32 %0, %1" : "+v"(a0), "+v"(b0));
        asm("v_permlane32_swap_b32 %0, %1" : "+v"(a1), "+v"(b1));
        unsigned pw[4] = {a0, a1, b0, b1};
        bf16x8 pa;
        __builtin_memcpy(&pa, pw, 16);
        int ks = jt * 2 + kp;
        lacc = __builtin_amdgcn_mfma_f32_32x32x16_bf16(pa, onesf, lacc, 0, 0, 0);
        {
          int rv = l32;                  // d-half 0
          bf16x8 vb = *(const bf16x8*)&Vb_[rv * 64 +
                                           (((ks * 2 + hf) ^ (rv & 7)) << 3)];
          o0 = __builtin_amdgcn_mfma_f32_32x32x16_bf16(pa, vb, o0, 0, 0, 0);
        }
        {
          int rv = 32 + l32;             // d-half 1
          bf16x8 vb = *(const bf16x8*)&Vb_[rv * 64 +
                                           (((ks * 2 + hf) ^ (rv & 7)) << 3)];
          o1 = __builtin_amdgcn_mfma_f32_32x32x16_bf16(pa, vb, o1, 0, 0, 0);
        }
      }
    }
  }

  // epilogue: o/lacc regs hold q = (r&3)+8*(r>>2)+4*hf at d = l32 (+32);
  // lacc[r] = full softmax denominator for that q, replicated across lanes.
#pragma unroll
  for (int r = 0; r < 16; ++r) {
    int qrow = (r & 3) + 8 * (r >> 2) + 4 * hf;
    float li = 1.0f / lacc[r];
    int q = qbase + qrow;
    __bf16* dst = Xa + ((size_t)q * BATCH + b) * DM + hd * DKD;
    dst[l32]      = (__bf16)(o0[r] * li);
    dst[32 + l32] = (__bf16)(o1[r] * li);
  }
}

// ------------------------------------------------------------------- launcher
extern "C" void kernel_launch(void* const* d_in, const int* in_sizes, int n_in,
                              void* d_out, int out_size, void* d_ws,
                              size_t ws_size, hipStream_t stream) {
  (void)in_sizes; (void)n_in; (void)out_size; (void)ws_size;
  const float* query = (const float*)d_in[0];
  const float* key_  = (const float*)d_in[1];
  const float* value = (const float*)d_in[2];
  const float* Wq = (const float*)d_in[3];
  const float* bq = (const float*)d_in[4];
  const float* Wk = (const float*)d_in[5];
  const float* bk = (const float*)d_in[6];
  const float* Wv = (const float*)d_in[7];
  const float* bv = (const float*)d_in[8];
  const float* Wo = (const float*)d_in[9];
  const float* bo = (const float*)d_in[10];

  const size_t NX = (size_t)MROWS * DM;  // 4M elems
  const size_t NW = (size_t)DM * DM;     // 1M elems
  __bf16* p    = (__bf16*)d_ws;
  __bf16* Xq   = p; p += NX;             // also reused as Xa after gemm_qkv
  __bf16* Xk   = p; p += NX;
  __bf16* Xv   = p; p += NX;
  __bf16* Wqkv = p; p += 3 * NW;
  __bf16* Wob  = p; p += NW;
  __bf16* Qb   = p; p += NX;   // [H][B][S][DK], pre-scaled by QSCALE
  __bf16* Kb   = p; p += NX;   // [H][B][S][DK]
  __bf16* Vt   = p; p += NX;   // [H][B][DK][S]
  __bf16* Xa   = Xq;           // [S*B][D] (aliases Xq, dead after gemm_qkv)

  cvt_all<<<dim3((unsigned)(NX / 2048), 7), 256, 0, stream>>>(
      query, key_, value, Wq, Wk, Wv, Wo,
      Xq, Xk, Xv, Wqkv, Wqkv + NW, Wqkv + 2 * NW, Wob, (int)NX, (int)NW);

  gemm_qkv<<<dim3(DM / 128, MROWS / 128, 3), 256, 0, stream>>>(
      Xq, Xk, Xv, Wqkv, bq, bk, bv, Qb, Kb, Vt);
  flash_attn<<<dim3(512), 256, 0, stream>>>(Qb, Kb, Vt, Xa);
  gemm_out<<<dim3(DM / 128, MROWS / 64), 256, 0, stream>>>(
      Xa, Wob, bo, (float*)d_out);
}

// Round 8
// 213.516 us; speedup vs baseline: 1.1044x; 1.0594x over previous
//
#include <hip/hip_runtime.h>

// Problem constants
#define SEQ   2048
#define BATCH 2
#define DM    1024
#define NH    16
#define DKD   64
#define MROWS (SEQ*BATCH)   // 4096 rows of the [S,B,D] matrices

#define QSCALE 0.18033688011112042f   // (1/8)*log2(e), folded into Q projection

using bf16x8 = __attribute__((ext_vector_type(8))) __bf16;  // MFMA A/B frag (4 VGPRs)
using bf16x4 = __attribute__((ext_vector_type(4))) __bf16;  // 8B pack
using bf16x2 = __attribute__((ext_vector_type(2))) __bf16;  // 4B pack
using f32x4  = __attribute__((ext_vector_type(4))) float;   // MFMA C/D frag (16x16)
using f32x16 = __attribute__((ext_vector_type(16))) float;  // MFMA C/D frag (32x32)

// async global->LDS, 16B per lane; LDS dest must be wave-uniform base + lane*16
__device__ __forceinline__ void gld_lds16(const __bf16* g, __bf16* l) {
  __builtin_amdgcn_global_load_lds(
      (__attribute__((address_space(1))) void*)(g),
      (__attribute__((address_space(3))) void*)(l), 16, 0, 0);
}

// ------------------------------------------------------- fp32 -> bf16 (merged)
__global__ __launch_bounds__(256) void cvt_all(
    const float* __restrict__ s0, const float* __restrict__ s1,
    const float* __restrict__ s2, const float* __restrict__ s3,
    const float* __restrict__ s4, const float* __restrict__ s5,
    const float* __restrict__ s6,
    __bf16* __restrict__ d0, __bf16* __restrict__ d1, __bf16* __restrict__ d2,
    __bf16* __restrict__ d3, __bf16* __restrict__ d4, __bf16* __restrict__ d5,
    __bf16* __restrict__ d6, int n_big, int n_small) {
  int y = blockIdx.y;
  const float* s; __bf16* d;
  switch (y) {
    case 0: s = s0; d = d0; break;
    case 1: s = s1; d = d1; break;
    case 2: s = s2; d = d2; break;
    case 3: s = s3; d = d3; break;
    case 4: s = s4; d = d4; break;
    case 5: s = s5; d = d5; break;
    default: s = s6; d = d6; break;
  }
  int n = (y < 3) ? n_big : n_small;
  int i = (blockIdx.x * 256 + threadIdx.x) * 8;
  if (i >= n) return;
  const float4* sp = (const float4*)(s + i);
  float4 a = sp[0], b = sp[1];
  bf16x8 v;
  v[0]=(__bf16)a.x; v[1]=(__bf16)a.y; v[2]=(__bf16)a.z; v[3]=(__bf16)a.w;
  v[4]=(__bf16)b.x; v[5]=(__bf16)b.y; v[6]=(__bf16)b.z; v[7]=(__bf16)b.w;
  *(bf16x8*)(d + i) = v;
}

// ------------------------------------------- shared 128x128 GEMM-BT core, BK=64
// LDS tiles are [rows][64] with the XOR swizzle: the 16B granule at slot pp of
// row r holds global columns ((pp ^ (r&7))*8 .. +8). Staged via pre-swizzled
// GLOBAL source + linear LDS dest; frag reads XOR the granule with r&7.
__device__ __forceinline__ void gemm_core(const __bf16* __restrict__ A,
                                          const __bf16* __restrict__ Bt,
                                          __bf16* Ash, __bf16* Bsh,
                                          f32x4 acc[4][4], int m0, int n0) {
  const int K = DM;
  int tid = threadIdx.x;
  int lane = tid & 63, quad = lane >> 4, l16 = lane & 15, sw = l16 & 7;
  int w = tid >> 6;
  int wm = (w & 1) * 64, wn = (w >> 1) * 64;
  for (int k0 = 0; k0 < K; k0 += 64) {
    __syncthreads();
#pragma unroll
    for (int it = 0; it < 4; ++it) {
      int c   = tid + it * 256;          // 1024 chunks of 16B cover 128x64 bf16
      int row = c >> 3, pp = c & 7;
      int ko  = (pp ^ (row & 7)) << 3;   // pre-swizzled global column
      int base = (tid - lane + it * 256) * 8;  // wave-uniform LDS base (elems)
      gld_lds16(A  + (size_t)(m0 + row) * K + k0 + ko, Ash + base);
      gld_lds16(Bt + (size_t)(n0 + row) * K + k0 + ko, Bsh + base);
    }
    __syncthreads();  // drains vmcnt -> LDS valid
#pragma unroll
    for (int kk = 0; kk < 2; ++kk) {
      bf16x8 af[4], bfr[4];
#pragma unroll
      for (int mi = 0; mi < 4; mi++)
        af[mi] = *(const bf16x8*)&Ash[(wm + mi * 16 + l16) * 64 +
                                      (((kk * 4 + quad) ^ sw) << 3)];
#pragma unroll
      for (int ni = 0; ni < 4; ni++)
        bfr[ni] = *(const bf16x8*)&Bsh[(wn + ni * 16 + l16) * 64 +
                                       (((kk * 4 + quad) ^ sw) << 3)];
#pragma unroll
      for (int mi = 0; mi < 4; mi++)
#pragma unroll
        for (int ni = 0; ni < 4; ni++)
          acc[mi][ni] = __builtin_amdgcn_mfma_f32_16x16x32_bf16(
              af[mi], bfr[ni], acc[mi][ni], 0, 0, 0);
    }
  }
}

// ------------------------------------------ QKV projections, permuted bf16 out
// grid (32, 8, 3): blockIdx.x indexes m0 so XCD = flat%8 = x%8 groups 4
// m-panels per XCD (A-panel L2 reuse; B = 2MB fits L2). Previously x indexed
// n0 (only 8 values) -> every XCD streamed the whole A matrix.
// Q/K out: [H][B][S][DK]; V out: [H][B][DK][S]. Q pre-scaled by QSCALE.
__global__ __launch_bounds__(256, 3) void gemm_qkv(
    const __bf16* __restrict__ Xq, const __bf16* __restrict__ Xk,
    const __bf16* __restrict__ Xv, const __bf16* __restrict__ Wqkv,
    const float* __restrict__ bqp, const float* __restrict__ bkp,
    const float* __restrict__ bvp,
    __bf16* __restrict__ Qb, __bf16* __restrict__ Kb, __bf16* __restrict__ Vt) {
  __shared__ __bf16 Ash[128 * 64], Bsh[128 * 64];
  __shared__ __bf16 Esh[4][16 * 72];     // per-wave epilogue staging
  int z = blockIdx.z;
  const __bf16* A   = (z == 0) ? Xq : (z == 1) ? Xk : Xv;
  const __bf16* Bt  = Wqkv + (size_t)z * (DM * DM);
  const float* bias = (z == 0) ? bqp : (z == 1) ? bkp : bvp;
  int m0 = blockIdx.x * 128, n0 = blockIdx.y * 128;
  f32x4 acc[4][4] = {};
  gemm_core(A, Bt, Ash, Bsh, acc, m0, n0);

  int tid = threadIdx.x, lane = tid & 63, quad = lane >> 4, l16 = lane & 15;
  int w = tid >> 6, wm = (w & 1) * 64, wn = (w >> 1) * 64;
  __bf16* E = Esh[w];
  int n_base = n0 + wn;                  // 64-aligned -> one head per wave tile
  int hh = n_base >> 6;
  float scale = (z == 0) ? QSCALE : 1.0f;
  float bb[4];
#pragma unroll
  for (int ni = 0; ni < 4; ni++) bb[ni] = bias[n_base + ni * 16 + l16] * scale;

  if (z == 2) {
    // Vt[(hh*B+b)*64+dd][sg]: stage 16 dd-rows (one ni) at a time.
#pragma unroll
    for (int ni = 0; ni < 4; ni++) {
#pragma unroll
      for (int mi = 0; mi < 4; mi++) {
        int s0 = mi * 8 + quad * 2;      // local s (even)
        bf16x2 p0, p1;
        p0[0] = (__bf16)(acc[mi][ni][0] + bb[ni]);
        p0[1] = (__bf16)(acc[mi][ni][2] + bb[ni]);
        p1[0] = (__bf16)(acc[mi][ni][1] + bb[ni]);
        p1[1] = (__bf16)(acc[mi][ni][3] + bb[ni]);
        *(bf16x2*)&E[l16 * 72 + s0]      = p0;   // b = 0
        *(bf16x2*)&E[l16 * 72 + 32 + s0] = p1;   // b = 1
      }
      asm volatile("s_waitcnt lgkmcnt(0)" ::: "memory");
#pragma unroll
      for (int pass = 0; pass < 2; pass++) {
        int ddl = pass * 8 + (lane >> 3);
        int col = (lane & 7) * 8;
        bf16x8 v = *(const bf16x8*)&E[ddl * 72 + col];
        int b2 = col >> 5, sl = col & 31;
        int dd = ni * 16 + ddl;
        int sg = ((m0 + wm) >> 1) + sl;
        *(bf16x8*)&Vt[(((size_t)hh * BATCH + b2) * DKD + dd) * SEQ + sg] = v;
      }
      asm volatile("s_waitcnt lgkmcnt(0)" ::: "memory");
    }
  } else {
    __bf16* Out = (z == 0) ? Qb : Kb;
#pragma unroll
    for (int mi = 0; mi < 4; mi++) {
#pragma unroll
      for (int ni = 0; ni < 4; ni++)
#pragma unroll
        for (int r = 0; r < 4; r++)
          E[(quad * 4 + r) * 72 + ni * 16 + l16] =
              (__bf16)fmaf(acc[mi][ni][r], scale, bb[ni]);
      asm volatile("s_waitcnt lgkmcnt(0)" ::: "memory");
#pragma unroll
      for (int pass = 0; pass < 2; pass++) {
        int row16 = pass * 8 + (lane >> 3);
        int coll  = (lane & 7) * 8;
        bf16x8 v = *(const bf16x8*)&E[row16 * 72 + coll];
        int m = m0 + wm + mi * 16 + row16;
        int s = m >> 1, b2 = m & 1;
        *(bf16x8*)&Out[(((size_t)hh * BATCH + b2) * SEQ + s) * DKD + coll] = v;
      }
      asm volatile("s_waitcnt lgkmcnt(0)" ::: "memory");
    }
  }
}

// --------------------------- output projection, 128x128 tiles via gemm_core
// (was 64x128: 6 LDS reads per 8 MFMAs/wave; gemm_core is 8 per 32 -> half
// the LDS+staging per FLOP). grid (32, 8): x indexes m0 for XCD A-reuse.
// fp32 epilogue direct to global (no LDS round-trip needed).
__global__ __launch_bounds__(256, 3) void gemm_out(
    const __bf16* __restrict__ A, const __bf16* __restrict__ Bt,
    const float* __restrict__ bias, float* __restrict__ out) {
  __shared__ __bf16 Ash[128 * 64], Bsh[128 * 64];
  int m0 = blockIdx.x * 128, n0 = blockIdx.y * 128;
  f32x4 acc[4][4] = {};
  gemm_core(A, Bt, Ash, Bsh, acc, m0, n0);

  int tid = threadIdx.x;
  int lane = tid & 63, quad = lane >> 4, l16 = lane & 15;
  int w = tid >> 6;
  int wm = (w & 1) * 64, wn = (w >> 1) * 64;
#pragma unroll
  for (int ni = 0; ni < 4; ni++) {
    int n = n0 + wn + ni * 16 + l16;
    float bb = bias[n];
#pragma unroll
    for (int mi = 0; mi < 4; mi++) {
#pragma unroll
      for (int r = 0; r < 4; r++) {
        int m = m0 + wm + mi * 16 + quad * 4 + r;
        out[(size_t)m * DM + n] = acc[mi][ni][r] + bb;
      }
    }
  }
}

// -------------------------------------------------------------- flash attention
// v5 (round-5 verified 62.8us): 32x32 MFMA path, fully in-register softmax
// (T12). Round-6 (occupancy split) and round-7 (MFMA-l) both regressed ->
// this is the best-known flash structure; parked.
// Grid 512 x 4 waves; wave owns 32 q. Per tile: 16 ds_read_b128 (8 K + 8 V),
// no P round-trip. exp2 softmax (QSCALE folded into Q), l on split VALU
// chains, cvt_pk + permlane32_swap rebuild PV A-frags in-register.
// Block n: hb = n&31 (h=hb>>1, b=hb&1), qi = n>>5 -> XCD = hb%8 L2 locality.
__global__ __launch_bounds__(256, 2) void flash_attn(
    const __bf16* __restrict__ Qg, const __bf16* __restrict__ Kg,
    const __bf16* __restrict__ Vtg, __bf16* __restrict__ Xa) {
  __shared__ __bf16 Ksh[2][64 * 64];
  __shared__ __bf16 Vsh[2][64 * 64];
  int tid = threadIdx.x, w = tid >> 6, lane = tid & 63;
  int l32 = lane & 31, hf = lane >> 5;
  int n = blockIdx.x;
  int hb = n & 31, qi = n >> 5;
  int hd = hb >> 1, b = hb & 1, q0 = qi * 128;
  int qbase = q0 + w * 32;
  size_t hboff = ((size_t)hd * BATCH + b) * SEQ * DKD;
  const __bf16* Qp = Qg + hboff;
  const __bf16* Kp = Kg + hboff;
  const __bf16* Vp = Vtg + hboff;        // [DK][SEQ] within (h,b)

  // Q frags (MFMA B operand, 32x32x16): col q = l32, k-elems d = kd*16+hf*8+e
  bf16x8 qf[4];
#pragma unroll
  for (int kd = 0; kd < 4; kd++)
    qf[kd] = *(const bf16x8*)(
        Qp + (size_t)(qbase + l32) * DKD + kd * 16 + hf * 8);

  f32x16 o0 = {0,0,0,0,0,0,0,0,0,0,0,0,0,0,0,0};
  f32x16 o1 = {0,0,0,0,0,0,0,0,0,0,0,0,0,0,0,0};
  float l0 = 0.f, l1 = 0.f;              // split dep-chains

  // stage tile 0 into buf 0 (512 chunks K + 512 V over 256 threads)
#pragma unroll
  for (int it = 0; it < 2; ++it) {
    int c = tid + it * 256;
    int r = c >> 3, pp = c & 7;
    int off = (pp ^ (r & 7)) << 3;
    gld_lds16(Kp + (size_t)r * DKD + off, Ksh[0] + c * 8);
    gld_lds16(Vp + (size_t)r * SEQ + off, Vsh[0] + c * 8);
  }

  for (int t = 0; t < SEQ / 64; ++t) {
    __syncthreads();                       // drains DMA for buf[t&1]
    if (t + 1 < SEQ / 64) {
      int k0n = (t + 1) * 64, bn = (t + 1) & 1;
#pragma unroll
      for (int it = 0; it < 2; ++it) {
        int c = tid + it * 256;
        int r = c >> 3, pp = c & 7;
        int off = (pp ^ (r & 7)) << 3;
        gld_lds16(Kp + (size_t)(k0n + r) * DKD + off, Ksh[bn] + c * 8);
        gld_lds16(Vp + (size_t)r * SEQ + k0n + off, Vsh[bn] + c * 8);
      }
    }
    const __bf16* Kb_ = Ksh[t & 1];
    const __bf16* Vb_ = Vsh[t & 1];

#pragma unroll
    for (int jt = 0; jt < 2; ++jt) {
      // S^T = K . Q^T over this 32-j block
      int rk = jt * 32 + l32;
      f32x16 s = {0,0,0,0,0,0,0,0,0,0,0,0,0,0,0,0};
#pragma unroll
      for (int kd = 0; kd < 4; kd++) {
        bf16x8 kf = *(const bf16x8*)&Kb_[rk * 64 +
                                         (((kd * 2 + hf) ^ (rk & 7)) << 3)];
        s = __builtin_amdgcn_mfma_f32_32x32x16_bf16(kf, qf[kd], s, 0, 0, 0);
      }
      // exp2 + cvt_pk pack: L[bq][sl] holds bf16 pair (j = bq*8+4*hf + 2*sl,+1)
      unsigned L[4][2];
#pragma unroll
      for (int bq = 0; bq < 4; bq++) {
        float p0 = exp2f(s[4 * bq + 0]);
        float p1 = exp2f(s[4 * bq + 1]);
        float p2 = exp2f(s[4 * bq + 2]);
        float p3 = exp2f(s[4 * bq + 3]);
        l0 += p0 + p2;
        l1 += p1 + p3;
        asm("v_cvt_pk_bf16_f32 %0, %1, %2" : "=v"(L[bq][0]) : "v"(p0), "v"(p1));
        asm("v_cvt_pk_bf16_f32 %0, %1, %2" : "=v"(L[bq][1]) : "v"(p2), "v"(p3));
      }
      // cross-half exchange + PV, per 16-j mfma slice
#pragma unroll
      for (int kp = 0; kp < 2; kp++) {
        unsigned a0 = L[2 * kp][0], b0 = L[2 * kp + 1][0];
        unsigned a1 = L[2 * kp][1], b1 = L[2 * kp + 1][1];
        // after swap: a' = [a_lo | b_lo] (pa words 0..1), b' = [a_hi | b_hi]
        asm("v_permlane32_swap_b32 %0, %1" : "+v"(a0), "+v"(b0));
        asm("v_permlane32_swap_b32 %0, %1" : "+v"(a1), "+v"(b1));
        unsigned pw[4] = {a0, a1, b0, b1};
        bf16x8 pa;
        __builtin_memcpy(&pa, pw, 16);
        int ks = jt * 2 + kp;
        {
          int rv = l32;                  // d-half 0
          bf16x8 vb = *(const bf16x8*)&Vb_[rv * 64 +
                                           (((ks * 2 + hf) ^ (rv & 7)) << 3)];
          o0 = __builtin_amdgcn_mfma_f32_32x32x16_bf16(pa, vb, o0, 0, 0, 0);
        }
        {
          int rv = 32 + l32;             // d-half 1
          bf16x8 vb = *(const bf16x8*)&Vb_[rv * 64 +
                                           (((ks * 2 + hf) ^ (rv & 7)) << 3)];
          o1 = __builtin_amdgcn_mfma_f32_32x32x16_bf16(pa, vb, o1, 0, 0, 0);
        }
      }
    }
  }

  // l: lane halves hold disjoint j-subsets for the same q = l32
  float l_ = l0 + l1;
  l_ += __shfl_xor(l_, 32, 64);
  float linv = 1.0f / l_;

  // epilogue: o regs hold q = (r&3)+8*(r>>2)+4*hf at d = l32 (+32)
#pragma unroll
  for (int r = 0; r < 16; ++r) {
    int qrow = (r & 3) + 8 * (r >> 2) + 4 * hf;
    float li = __shfl(linv, qrow, 64);   // linv lives at lane == q (both halves)
    int q = qbase + qrow;
    __bf16* dst = Xa + ((size_t)q * BATCH + b) * DM + hd * DKD;
    dst[l32]      = (__bf16)(o0[r] * li);
    dst[32 + l32] = (__bf16)(o1[r] * li);
  }
}

// ------------------------------------------------------------------- launcher
extern "C" void kernel_launch(void* const* d_in, const int* in_sizes, int n_in,
                              void* d_out, int out_size, void* d_ws,
                              size_t ws_size, hipStream_t stream) {
  (void)in_sizes; (void)n_in; (void)out_size; (void)ws_size;
  const float* query = (const float*)d_in[0];
  const float* key_  = (const float*)d_in[1];
  const float* value = (const float*)d_in[2];
  const float* Wq = (const float*)d_in[3];
  const float* bq = (const float*)d_in[4];
  const float* Wk = (const float*)d_in[5];
  const float* bk = (const float*)d_in[6];
  const float* Wv = (const float*)d_in[7];
  const float* bv = (const float*)d_in[8];
  const float* Wo = (const float*)d_in[9];
  const float* bo = (const float*)d_in[10];

  const size_t NX = (size_t)MROWS * DM;  // 4M elems
  const size_t NW = (size_t)DM * DM;     // 1M elems
  __bf16* p    = (__bf16*)d_ws;
  __bf16* Xq   = p; p += NX;             // also reused as Xa after gemm_qkv
  __bf16* Xk   = p; p += NX;
  __bf16* Xv   = p; p += NX;
  __bf16* Wqkv = p; p += 3 * NW;
  __bf16* Wob  = p; p += NW;
  __bf16* Qb   = p; p += NX;   // [H][B][S][DK], pre-scaled by QSCALE
  __bf16* Kb   = p; p += NX;   // [H][B][S][DK]
  __bf16* Vt   = p; p += NX;   // [H][B][DK][S]
  __bf16* Xa   = Xq;           // [S*B][D] (aliases Xq, dead after gemm_qkv)

  cvt_all<<<dim3((unsigned)(NX / 2048), 7), 256, 0, stream>>>(
      query, key_, value, Wq, Wk, Wv, Wo,
      Xq, Xk, Xv, Wqkv, Wqkv + NW, Wqkv + 2 * NW, Wob, (int)NX, (int)NW);

  gemm_qkv<<<dim3(MROWS / 128, DM / 128, 3), 256, 0, stream>>>(
      Xq, Xk, Xv, Wqkv, bq, bk, bv, Qb, Kb, Vt);
  flash_attn<<<dim3(512), 256, 0, stream>>>(Qb, Kb, Vt, Xa);
  gemm_out<<<dim3(MROWS / 128, DM / 128), 256, 0, stream>>>(
      Xa, Wob, bo, (float*)d_out);
}